// Round 31
// baseline (58.345 us; speedup 1.0000x reference)
//
#include <hip/hip_runtime.h>
#include <hip/hip_bf16.h>
#include <hip/hip_fp16.h>

// SASA local self-attention, fused. Round 31: 16x8 tiles (1024 blocks, 4/CU) +
// single K/V LDS buffer with V RECOMPUTED after Phase A (no register parking).
//  - 256 thr/block, halo 308px, LDS 29.2KB -> 4 independent blocks/CU:
//    barriers stall 4 waves not 16; blocks overlap phases.
//  - two-pass softmax separates K and V; V rebuilt from s_w weights + L2-hot x.
//  - MFMA projection (r27), dot2 attention (r16), XCD swizzle re-derived.
// B=4, CIN=COUT=256, H=W=64, G=8, CG=32, K=7, PAD=3.
#define TSX  16
#define TSY  8
#define HS   22          // halo width  (16 + 6)
#define HP   308         // 22 * 14 halo pixels
#define NT   20          // ceil(308/16) MFMA pixel tiles
#define KDW  18          // u32 stride per halo pixel (72B)
#define KK   7
#define K2   49

typedef _Float16 h2    __attribute__((ext_vector_type(2)));
typedef _Float16 f16x8 __attribute__((ext_vector_type(8)));
typedef float    f32x4 __attribute__((ext_vector_type(4)));
union U32H { unsigned u; h2 h; __half2 p; };

__device__ __forceinline__ h2 pkrtz(float a, float b) {
    auto r = __builtin_amdgcn_cvt_pkrtz(a, b);
    union { decltype(r) i; h2 o; } c; c.i = r;
    return c.o;
}
__device__ __forceinline__ float dot2(h2 a, h2 b, float c) {
#if __has_builtin(__builtin_amdgcn_fdot2)
    return __builtin_amdgcn_fdot2(a, b, c, false);
#else
    return fmaf((float)a.x, (float)b.x, fmaf((float)a.y, (float)b.y, c));
#endif
}
__device__ __forceinline__ float dot2u(unsigned wu, h2 b, float c) {
    U32H w; w.u = wu; return dot2(w.h, b, c);
}
__device__ __forceinline__ float pswap(float v) {
#if __has_builtin(__builtin_amdgcn_mov_dpp)
    int j = __builtin_amdgcn_mov_dpp(__float_as_int(v), 0xB1, 0xF, 0xF, true);
    return __int_as_float(j);
#else
    return __shfl_xor(v, 1, 64);
#endif
}

__global__ __attribute__((amdgpu_flat_work_group_size(256, 256), amdgpu_waves_per_eu(4, 8)))
void sasa_fused_kernel(const float* __restrict__ x,
                       const float* __restrict__ wq,
                       const float* __restrict__ wk,
                       const float* __restrict__ wv,
                       const float* __restrict__ row_emb,
                       const float* __restrict__ col_emb,
                       float* __restrict__ out)
{
    __shared__ h2       s_w[1536];         // [m(k,v,q)*2+hh][cp][co], 6 KB
    __shared__ float    s_emb[224];        // E[c][t], 0.9 KB
    __shared__ unsigned s_kv[HP * KDW];    // K (Phase A) then V (PV), 22.2 KB

    const int tid = threadIdx.x;

    // ---- XCD-bijective swizzle: 32 spatial tiles of each (b,g) share an XCD ----
    const int lin  = blockIdx.x + (blockIdx.y << 2) + (blockIdx.z << 5); // [0,1024)
    const int xcd  = lin & 7;
    const int slot = lin >> 3;               // [0,128)
    const int zg   = xcd + ((slot >> 5) << 3);   // 4 (b,g) groups per xcd
    const int sp   = slot & 31;
    const int b    = zg >> 3;
    const int g    = zg & 7;
    const int y0   = (sp >> 2) * TSY;        // 8 rows of tiles
    const int x0   = (sp & 3) * TSX;         // 4 cols of tiles

    const float* xg = x + (size_t)(b * 256 + g * 32) * 4096;

    // ---- stage all 3 weight matrices as f16 pairs + emb slice (256 thr) ----
    #pragma unroll
    for (int i = 0; i < 2; ++i) {
        const int e   = tid + i * 256;       // [0,512)
        const int cp  = e & 15;
        const int cog = e >> 4;
        const int hh  = cog >> 4;
        const int co  = cog & 15;
        const int di  = (hh * 16 + cp) * 16 + co;
        float2 a = ((const float2*)(wk + g * 1024))[e]; s_w[di]        = pkrtz(a.x, a.y);
        float2 v = ((const float2*)(wv + g * 1024))[e]; s_w[512 + di]  = pkrtz(v.x, v.y);
        float2 q = ((const float2*)(wq + g * 1024))[e]; s_w[1024 + di] = pkrtz(q.x, q.y);
    }
    if (tid < 224) {
        int c = tid / KK, t = tid - c * KK;
        s_emb[tid] = (g < 4) ? row_emb[(g * 32 + c) * KK + t]
                             : col_emb[((g - 4) * 32 + c) * KK + t];
    }
    __syncthreads();

    // ---- MFMA lane mapping ----
    const int lane = tid & 63;
    const int wid  = tid >> 6;        // 0..3
    const int lrow = lane & 15;       // A row / B col / D col
    const int lgrp = lane >> 4;       // k group 0..3

    // ---- K halo projection via MFMA -> s_kv ----
    {
        f16x8 bk0, bk1;
        #pragma unroll
        for (int j = 0; j < 4; ++j) {
            const int cp = lgrp * 4 + j;
            h2 pk0 = s_w[(0 * 16 + cp) * 16 + lrow];
            h2 pk1 = s_w[(1 * 16 + cp) * 16 + lrow];
            bk0[2 * j] = pk0.x; bk0[2 * j + 1] = pk0.y;
            bk1[2 * j] = pk1.x; bk1[2 * j + 1] = pk1.y;
        }
        _Float16* sk16 = (_Float16*)s_kv;
        const f32x4 zero = {0.f, 0.f, 0.f, 0.f};
        #pragma unroll
        for (int it = 0; it < 5; ++it) {
            const int t = wid + it * 4;      // 0..19
            const int hp = t * 16 + lrow;
            f16x8 a;
            bool valid = false;
            int gy = 0, gx = 0;
            if (hp < HP) {
                const int hy = hp / HS, hx = hp - hy * HS;
                gy = y0 + hy - 3; gx = x0 + hx - 3;
                valid = ((unsigned)gy < 64u) && ((unsigned)gx < 64u);
            }
            if (valid) {
                const float* xp = xg + gy * 64 + gx + (size_t)(lgrp * 8) * 4096;
                #pragma unroll
                for (int i2 = 0; i2 < 4; ++i2) {
                    h2 pr = pkrtz(xp[(2 * i2) * 4096], xp[(2 * i2 + 1) * 4096]);
                    a[2 * i2] = pr.x; a[2 * i2 + 1] = pr.y;
                }
            } else {
                #pragma unroll
                for (int i = 0; i < 8; ++i) a[i] = (_Float16)0.f;
            }
            f32x4 dk0 = __builtin_amdgcn_mfma_f32_16x16x32_f16(a, bk0, zero, 0, 0, 0);
            f32x4 dk1 = __builtin_amdgcn_mfma_f32_16x16x32_f16(a, bk1, zero, 0, 0, 0);
            #pragma unroll
            for (int r = 0; r < 4; ++r) {
                const int hpo = t * 16 + lgrp * 4 + r;
                if (hpo < HP) {
                    const int base = hpo * 36;
                    sk16[base + lrow]      = (_Float16)dk0[r];
                    sk16[base + 16 + lrow] = (_Float16)dk1[r];
                }
            }
        }
    }

    // ---- q projection: thread (p, h) owns 16 q channels ----
    const int p  = tid >> 1;          // 0..127
    const int h  = tid & 1;
    const int tx = p & 15, ty = p >> 4;   // ty 0..7
    const int yy = y0 + ty, xx = x0 + tx;
    float accQ[16];
    #pragma unroll
    for (int c = 0; c < 16; ++c) accQ[c] = 0.f;
    {
        const float* xp = xg + yy * 64 + xx;
        h2 xv2[16];
        #pragma unroll
        for (int cp = 0; cp < 16; ++cp)
            xv2[cp] = pkrtz(xp[(2 * cp) * 4096], xp[(2 * cp + 1) * 4096]);
        const h2* wqp = s_w + 1024 + h * 256;
        #pragma unroll
        for (int cp = 0; cp < 16; ++cp) {
            h2 xv = xv2[cp];
            const uint4* wqr = (const uint4*)(wqp + cp * 16);
            uint4 qw[4] = { wqr[0], wqr[1], wqr[2], wqr[3] };
            const unsigned* qwu = (const unsigned*)qw;
            #pragma unroll
            for (int co = 0; co < 16; ++co)
                accQ[co] = dot2u(qwu[co], xv, accQ[co]);
        }
    }

    // ---- qe[7] = q . emb, pair-combined via DPP ----
    float qe[KK];
    #pragma unroll
    for (int t = 0; t < KK; ++t) {
        float a = 0.f;
        #pragma unroll
        for (int c = 0; c < 16; ++c)
            a = fmaf(accQ[c], s_emb[(h * 16 + c) * KK + t], a);
        qe[t] = a + 0.f;
    }
    #pragma unroll
    for (int t = 0; t < KK; ++t)
        qe[t] += pswap(qe[t]);

    // ---- pack q to f16 pairs ----
    h2 q2[8];
    #pragma unroll
    for (int j = 0; j < 8; ++j) q2[j] = pkrtz(accQ[2 * j], accQ[2 * j + 1]);

    __syncthreads();   // K staged

    const int rowsel = (g < 4) ? 1 : 0;

    // ---- Phase A: 49 logits from K buffer ----
    float lg[K2];
    const unsigned* kb = s_kv + h * 8;
    #pragma unroll
    for (int tp = 0; tp < 24; ++tp) {
        const int t0 = 2 * tp, t1 = t0 + 1;
        const int ki0 = t0 / KK, kj0 = t0 - ki0 * KK;
        const int ki1 = t1 / KK, kj1 = t1 - ki1 * KK;
        const uint2* kp0 = (const uint2*)(kb + ((ty + ki0) * HS + tx + kj0) * KDW);
        const uint2* kp1 = (const uint2*)(kb + ((ty + ki1) * HS + tx + kj1) * KDW);
        uint2 a0 = kp0[0], a1 = kp0[1], a2 = kp0[2], a3 = kp0[3];
        uint2 b0 = kp1[0], b1 = kp1[1], b2 = kp1[2], b3 = kp1[3];
        float p0 = 0.f, p1 = 0.f;
        p0 = dot2u(a0.x, q2[0], p0);  p1 = dot2u(b0.x, q2[0], p1);
        p0 = dot2u(a0.y, q2[1], p0);  p1 = dot2u(b0.y, q2[1], p1);
        p0 = dot2u(a1.x, q2[2], p0);  p1 = dot2u(b1.x, q2[2], p1);
        p0 = dot2u(a1.y, q2[3], p0);  p1 = dot2u(b1.y, q2[3], p1);
        p0 = dot2u(a2.x, q2[4], p0);  p1 = dot2u(b2.x, q2[4], p1);
        p0 = dot2u(a2.y, q2[5], p0);  p1 = dot2u(b2.y, q2[5], p1);
        p0 = dot2u(a3.x, q2[6], p0);  p1 = dot2u(b3.x, q2[6], p1);
        p0 = dot2u(a3.y, q2[7], p0);  p1 = dot2u(b3.y, q2[7], p1);
        lg[t0] = p0 + pswap(p0) + (rowsel ? qe[ki0] : qe[kj0]);
        lg[t1] = p1 + pswap(p1) + (rowsel ? qe[ki1] : qe[kj1]);
    }
    {   // t = 48 (ki=6, kj=6)
        const uint2* kp = (const uint2*)(kb + ((ty + 6) * HS + tx + 6) * KDW);
        uint2 a0 = kp[0], a1 = kp[1], a2 = kp[2], a3 = kp[3];
        float p0 = 0.f;
        p0 = dot2u(a0.x, q2[0], p0); p0 = dot2u(a0.y, q2[1], p0);
        p0 = dot2u(a1.x, q2[2], p0); p0 = dot2u(a1.y, q2[3], p0);
        p0 = dot2u(a2.x, q2[4], p0); p0 = dot2u(a2.y, q2[5], p0);
        p0 = dot2u(a3.x, q2[6], p0); p0 = dot2u(a3.y, q2[7], p0);
        lg[48] = p0 + pswap(p0) + qe[6];
    }

    __syncthreads();   // Phase A reads of K complete

    // ---- V halo projection via MFMA (recompute; s_w still holds wv; x is L2-hot) ----
    {
        f16x8 bv0, bv1;
        #pragma unroll
        for (int j = 0; j < 4; ++j) {
            const int cp = lgrp * 4 + j;
            h2 pv0 = s_w[512 + (0 * 16 + cp) * 16 + lrow];
            h2 pv1 = s_w[512 + (1 * 16 + cp) * 16 + lrow];
            bv0[2 * j] = pv0.x; bv0[2 * j + 1] = pv0.y;
            bv1[2 * j] = pv1.x; bv1[2 * j + 1] = pv1.y;
        }
        _Float16* sv16 = (_Float16*)s_kv;
        const f32x4 zero = {0.f, 0.f, 0.f, 0.f};
        #pragma unroll
        for (int it = 0; it < 5; ++it) {
            const int t = wid + it * 4;
            const int hp = t * 16 + lrow;
            f16x8 a;
            bool valid = false;
            int gy = 0, gx = 0;
            if (hp < HP) {
                const int hy = hp / HS, hx = hp - hy * HS;
                gy = y0 + hy - 3; gx = x0 + hx - 3;
                valid = ((unsigned)gy < 64u) && ((unsigned)gx < 64u);
            }
            if (valid) {
                const float* xp = xg + gy * 64 + gx + (size_t)(lgrp * 8) * 4096;
                #pragma unroll
                for (int i2 = 0; i2 < 4; ++i2) {
                    h2 pr = pkrtz(xp[(2 * i2) * 4096], xp[(2 * i2 + 1) * 4096]);
                    a[2 * i2] = pr.x; a[2 * i2 + 1] = pr.y;
                }
            } else {
                #pragma unroll
                for (int i = 0; i < 8; ++i) a[i] = (_Float16)0.f;
            }
            f32x4 dv0 = __builtin_amdgcn_mfma_f32_16x16x32_f16(a, bv0, zero, 0, 0, 0);
            f32x4 dv1 = __builtin_amdgcn_mfma_f32_16x16x32_f16(a, bv1, zero, 0, 0, 0);
            #pragma unroll
            for (int r = 0; r < 4; ++r) {
                const int hpo = t * 16 + lgrp * 4 + r;
                if (hpo < HP) {
                    const int base = hpo * 36;
                    sv16[base + lrow]      = (_Float16)dv0[r];
                    sv16[base + 16 + lrow] = (_Float16)dv1[r];
                }
            }
        }
    }

    // ---- Phase B: tree max, independent exps, tree sum (register-only) ----
    float m0 = lg[0], m1 = lg[1], m2 = lg[2], m3 = lg[3];
    #pragma unroll
    for (int t = 4; t < 48; t += 4) {
        m0 = fmaxf(m0, lg[t]);
        m1 = fmaxf(m1, lg[t + 1]);
        m2 = fmaxf(m2, lg[t + 2]);
        m3 = fmaxf(m3, lg[t + 3]);
    }
    const float mx = fmaxf(fmaxf(m0, m1), fmaxf(m2, fmaxf(m3, lg[48])));

    float s0 = 0.f, s1 = 0.f, s2 = 0.f, s3 = 0.f;
    #pragma unroll
    for (int t = 0; t < K2; ++t) {
        float pe = __expf(lg[t] - mx);
        lg[t] = pe;
        if ((t & 3) == 0) s0 += pe;
        else if ((t & 3) == 1) s1 += pe;
        else if ((t & 3) == 2) s2 += pe;
        else s3 += pe;
    }
    const float s = (s0 + s1) + (s2 + s3);

    __syncthreads();   // V staged

    // ---- PV: 2 positions in flight, pure f16 fma accumulation ----
    __half2 o2[8];
    #pragma unroll
    for (int j = 0; j < 8; ++j) o2[j] = __float2half2_rn(0.f);

    const unsigned* vb = s_kv + h * 8;
    #pragma unroll
    for (int tp = 0; tp < 24; ++tp) {
        const int t0 = 2 * tp, t1 = t0 + 1;
        const int ki0 = t0 / KK, kj0 = t0 - ki0 * KK;
        const int ki1 = t1 / KK, kj1 = t1 - ki1 * KK;
        const uint2* vp0 = (const uint2*)(vb + ((ty + ki0) * HS + tx + kj0) * KDW);
        const uint2* vp1 = (const uint2*)(vb + ((ty + ki1) * HS + tx + kj1) * KDW);
        uint2 a0 = vp0[0], a1 = vp0[1], a2 = vp0[2], a3 = vp0[3];
        uint2 b0 = vp1[0], b1 = vp1[1], b2 = vp1[2], b3 = vp1[3];
        const __half2 pe0 = __float2half2_rn(lg[t0]);
        const __half2 pe1 = __float2half2_rn(lg[t1]);
        U32H c0, c1, c2, c3, c4, c5, c6, c7;
        c0.u = a0.x; c1.u = a0.y; c2.u = a1.x; c3.u = a1.y;
        c4.u = a2.x; c5.u = a2.y; c6.u = a3.x; c7.u = a3.y;
        o2[0] = __hfma2(c0.p, pe0, o2[0]);
        o2[1] = __hfma2(c1.p, pe0, o2[1]);
        o2[2] = __hfma2(c2.p, pe0, o2[2]);
        o2[3] = __hfma2(c3.p, pe0, o2[3]);
        o2[4] = __hfma2(c4.p, pe0, o2[4]);
        o2[5] = __hfma2(c5.p, pe0, o2[5]);
        o2[6] = __hfma2(c6.p, pe0, o2[6]);
        o2[7] = __hfma2(c7.p, pe0, o2[7]);
        c0.u = b0.x; c1.u = b0.y; c2.u = b1.x; c3.u = b1.y;
        c4.u = b2.x; c5.u = b2.y; c6.u = b3.x; c7.u = b3.y;
        o2[0] = __hfma2(c0.p, pe1, o2[0]);
        o2[1] = __hfma2(c1.p, pe1, o2[1]);
        o2[2] = __hfma2(c2.p, pe1, o2[2]);
        o2[3] = __hfma2(c3.p, pe1, o2[3]);
        o2[4] = __hfma2(c4.p, pe1, o2[4]);
        o2[5] = __hfma2(c5.p, pe1, o2[5]);
        o2[6] = __hfma2(c6.p, pe1, o2[6]);
        o2[7] = __hfma2(c7.p, pe1, o2[7]);
    }
    {   // t = 48
        const uint2* vp = (const uint2*)(vb + ((ty + 6) * HS + tx + 6) * KDW);
        uint2 a0 = vp[0], a1 = vp[1], a2 = vp[2], a3 = vp[3];
        const __half2 pe0 = __float2half2_rn(lg[48]);
        U32H c0, c1, c2, c3, c4, c5, c6, c7;
        c0.u = a0.x; c1.u = a0.y; c2.u = a1.x; c3.u = a1.y;
        c4.u = a2.x; c5.u = a2.y; c6.u = a3.x; c7.u = a3.y;
        o2[0] = __hfma2(c0.p, pe0, o2[0]);
        o2[1] = __hfma2(c1.p, pe0, o2[1]);
        o2[2] = __hfma2(c2.p, pe0, o2[2]);
        o2[3] = __hfma2(c3.p, pe0, o2[3]);
        o2[4] = __hfma2(c4.p, pe0, o2[4]);
        o2[5] = __hfma2(c5.p, pe0, o2[5]);
        o2[6] = __hfma2(c6.p, pe0, o2[6]);
        o2[7] = __hfma2(c7.p, pe0, o2[7]);
    }

    // ---- write 16 channels ----
    const float inv = 1.0f / s;
    float* op = out + (size_t)(b * 256 + g * 32 + h * 16) * 4096 + yy * 64 + xx;
    #pragma unroll
    for (int j = 0; j < 8; ++j) {
        float2 f = __half22float2(o2[j]);
        op[(2 * j) * 4096]     = f.x * inv;
        op[(2 * j + 1) * 4096] = f.y * inv;
    }
}

extern "C" void kernel_launch(void* const* d_in, const int* in_sizes, int n_in,
                              void* d_out, int out_size, void* d_ws, size_t ws_size,
                              hipStream_t stream) {
    const float* x       = (const float*)d_in[0];
    const float* wq      = (const float*)d_in[1];
    const float* wk      = (const float*)d_in[2];
    const float* wv      = (const float*)d_in[3];
    const float* row_emb = (const float*)d_in[4];
    const float* col_emb = (const float*)d_in[5];
    float* out = (float*)d_out;

    dim3 grid(4, 8, 32);   // (W/16, H/8, B*G), remapped inside (XCD swizzle)
    dim3 block(256);
    sasa_fused_kernel<<<grid, block, 0, stream>>>(x, wq, wk, wv, row_emb, col_emb, out);
}

// Round 32
// 41.171 us; speedup vs baseline: 1.4171x; 1.4171x over previous
//
#include <hip/hip_runtime.h>
#include <hip/hip_bf16.h>
#include <hip/hip_fp16.h>

// SASA local self-attention, fused. Round 32: 16x8 tiles, DUAL K/V buffers,
// single-pass MFMA projection (r27 pattern; r31's V-recompute caused the
// spill+refetch regression, its 16x8 indexing was numerically validated).
//  - 1024 blocks x 256 thr; halo 308 px; LDS 51.3 KB -> 3 independent
//    blocks/CU (12 waves in 3 blocks vs r27's 16 in 2 lock-stepped).
// B=4, CIN=COUT=256, H=W=64, G=8, CG=32, K=7, PAD=3.
#define TSX  16
#define TSY  8
#define HS   22          // halo width  (16 + 6)
#define HP   308         // 22 * 14 halo pixels
#define KDW  18          // u32 stride per halo pixel (72B)
#define KK   7
#define K2   49

typedef _Float16 h2    __attribute__((ext_vector_type(2)));
typedef _Float16 f16x8 __attribute__((ext_vector_type(8)));
typedef float    f32x4 __attribute__((ext_vector_type(4)));
union U32H { unsigned u; h2 h; __half2 p; };

__device__ __forceinline__ h2 pkrtz(float a, float b) {
    auto r = __builtin_amdgcn_cvt_pkrtz(a, b);
    union { decltype(r) i; h2 o; } c; c.i = r;
    return c.o;
}
__device__ __forceinline__ float dot2(h2 a, h2 b, float c) {
#if __has_builtin(__builtin_amdgcn_fdot2)
    return __builtin_amdgcn_fdot2(a, b, c, false);
#else
    return fmaf((float)a.x, (float)b.x, fmaf((float)a.y, (float)b.y, c));
#endif
}
__device__ __forceinline__ float dot2u(unsigned wu, h2 b, float c) {
    U32H w; w.u = wu; return dot2(w.h, b, c);
}
__device__ __forceinline__ float pswap(float v) {
#if __has_builtin(__builtin_amdgcn_mov_dpp)
    int j = __builtin_amdgcn_mov_dpp(__float_as_int(v), 0xB1, 0xF, 0xF, true);
    return __int_as_float(j);
#else
    return __shfl_xor(v, 1, 64);
#endif
}

__global__ __attribute__((amdgpu_flat_work_group_size(256, 256), amdgpu_waves_per_eu(4, 4)))
void sasa_fused_kernel(const float* __restrict__ x,
                       const float* __restrict__ wq,
                       const float* __restrict__ wk,
                       const float* __restrict__ wv,
                       const float* __restrict__ row_emb,
                       const float* __restrict__ col_emb,
                       float* __restrict__ out)
{
    __shared__ h2       s_w[1536];         // [m(k,v,q)*2+hh][cp][co], 6 KB
    __shared__ float    s_emb[224];        // E[c][t], 0.9 KB
    __shared__ unsigned s_ku[HP * KDW];    // K halo, 22.2 KB
    __shared__ unsigned s_vu[HP * KDW];    // V halo, 22.2 KB

    const int tid = threadIdx.x;

    // ---- XCD-bijective swizzle: 32 spatial tiles of each (b,g) share an XCD ----
    const int lin  = blockIdx.x + (blockIdx.y << 2) + (blockIdx.z << 5); // [0,1024)
    const int xcd  = lin & 7;
    const int slot = lin >> 3;               // [0,128)
    const int zg   = xcd + ((slot >> 5) << 3);   // 4 (b,g) groups per xcd
    const int sp   = slot & 31;
    const int b    = zg >> 3;
    const int g    = zg & 7;
    const int y0   = (sp >> 2) * TSY;        // 8 rows of tiles
    const int x0   = (sp & 3) * TSX;         // 4 cols of tiles

    const float* xg = x + (size_t)(b * 256 + g * 32) * 4096;

    // ---- stage all 3 weight matrices as f16 pairs + emb slice (256 thr) ----
    #pragma unroll
    for (int i = 0; i < 2; ++i) {
        const int e   = tid + i * 256;       // [0,512)
        const int cp  = e & 15;
        const int cog = e >> 4;
        const int hh  = cog >> 4;
        const int co  = cog & 15;
        const int di  = (hh * 16 + cp) * 16 + co;
        float2 a = ((const float2*)(wk + g * 1024))[e]; s_w[di]        = pkrtz(a.x, a.y);
        float2 v = ((const float2*)(wv + g * 1024))[e]; s_w[512 + di]  = pkrtz(v.x, v.y);
        float2 q = ((const float2*)(wq + g * 1024))[e]; s_w[1024 + di] = pkrtz(q.x, q.y);
    }
    if (tid < 224) {
        int c = tid / KK, t = tid - c * KK;
        s_emb[tid] = (g < 4) ? row_emb[(g * 32 + c) * KK + t]
                             : col_emb[((g - 4) * 32 + c) * KK + t];
    }
    __syncthreads();

    // ---- MFMA lane mapping ----
    const int lane = tid & 63;
    const int wid  = tid >> 6;        // 0..3
    const int lrow = lane & 15;       // A row / B col / D col
    const int lgrp = lane >> 4;       // k group 0..3

    // ---- K/V halo projection via MFMA (single pass, r27 pattern) ----
    {
        f16x8 bk0, bk1, bv0, bv1;
        #pragma unroll
        for (int j = 0; j < 4; ++j) {
            const int cp = lgrp * 4 + j;
            h2 pk0 = s_w[(0 * 16 + cp) * 16 + lrow];
            h2 pk1 = s_w[(1 * 16 + cp) * 16 + lrow];
            h2 pv0 = s_w[512 + (0 * 16 + cp) * 16 + lrow];
            h2 pv1 = s_w[512 + (1 * 16 + cp) * 16 + lrow];
            bk0[2 * j] = pk0.x; bk0[2 * j + 1] = pk0.y;
            bk1[2 * j] = pk1.x; bk1[2 * j + 1] = pk1.y;
            bv0[2 * j] = pv0.x; bv0[2 * j + 1] = pv0.y;
            bv1[2 * j] = pv1.x; bv1[2 * j + 1] = pv1.y;
        }
        _Float16* sk16 = (_Float16*)s_ku;
        _Float16* sv16 = (_Float16*)s_vu;
        const f32x4 zero = {0.f, 0.f, 0.f, 0.f};
        #pragma unroll 1
        for (int it = 0; it < 5; ++it) {
            const int t = wid + it * 4;      // 0..19
            const int hp = t * 16 + lrow;
            f16x8 a;
            bool valid = false;
            int gy = 0, gx = 0;
            if (hp < HP) {
                const int hy = hp / HS, hx = hp - hy * HS;
                gy = y0 + hy - 3; gx = x0 + hx - 3;
                valid = ((unsigned)gy < 64u) && ((unsigned)gx < 64u);
            }
            if (valid) {
                const float* xp = xg + gy * 64 + gx + (size_t)(lgrp * 8) * 4096;
                #pragma unroll
                for (int i2 = 0; i2 < 4; ++i2) {
                    h2 pr = pkrtz(xp[(2 * i2) * 4096], xp[(2 * i2 + 1) * 4096]);
                    a[2 * i2] = pr.x; a[2 * i2 + 1] = pr.y;
                }
            } else {
                #pragma unroll
                for (int i = 0; i < 8; ++i) a[i] = (_Float16)0.f;
            }
            f32x4 dk0 = __builtin_amdgcn_mfma_f32_16x16x32_f16(a, bk0, zero, 0, 0, 0);
            f32x4 dk1 = __builtin_amdgcn_mfma_f32_16x16x32_f16(a, bk1, zero, 0, 0, 0);
            f32x4 dv0 = __builtin_amdgcn_mfma_f32_16x16x32_f16(a, bv0, zero, 0, 0, 0);
            f32x4 dv1 = __builtin_amdgcn_mfma_f32_16x16x32_f16(a, bv1, zero, 0, 0, 0);
            #pragma unroll
            for (int r = 0; r < 4; ++r) {
                const int hpo = t * 16 + lgrp * 4 + r;
                if (hpo < HP) {
                    const int base = hpo * 36;
                    sk16[base + lrow]      = (_Float16)dk0[r];
                    sk16[base + 16 + lrow] = (_Float16)dk1[r];
                    sv16[base + lrow]      = (_Float16)dv0[r];
                    sv16[base + 16 + lrow] = (_Float16)dv1[r];
                }
            }
        }
    }

    // ---- q projection: thread (p, h) owns 16 q channels ----
    const int p  = tid >> 1;          // 0..127
    const int h  = tid & 1;
    const int tx = p & 15, ty = p >> 4;   // ty 0..7
    const int yy = y0 + ty, xx = x0 + tx;
    float accQ[16];
    #pragma unroll
    for (int c = 0; c < 16; ++c) accQ[c] = 0.f;
    {
        const float* xp = xg + yy * 64 + xx;
        h2 xv2[16];
        #pragma unroll
        for (int cp = 0; cp < 16; ++cp)
            xv2[cp] = pkrtz(xp[(2 * cp) * 4096], xp[(2 * cp + 1) * 4096]);
        const h2* wqp = s_w + 1024 + h * 256;
        #pragma unroll
        for (int cp = 0; cp < 16; ++cp) {
            h2 xv = xv2[cp];
            const uint4* wqr = (const uint4*)(wqp + cp * 16);
            uint4 qw[4] = { wqr[0], wqr[1], wqr[2], wqr[3] };
            const unsigned* qwu = (const unsigned*)qw;
            #pragma unroll
            for (int co = 0; co < 16; ++co)
                accQ[co] = dot2u(qwu[co], xv, accQ[co]);
        }
    }

    // ---- qe[7] = q . emb, pair-combined via DPP ----
    float qe[KK];
    #pragma unroll
    for (int t = 0; t < KK; ++t) {
        float a = 0.f;
        #pragma unroll
        for (int c = 0; c < 16; ++c)
            a = fmaf(accQ[c], s_emb[(h * 16 + c) * KK + t], a);
        qe[t] = a + 0.f;
    }
    #pragma unroll
    for (int t = 0; t < KK; ++t)
        qe[t] += pswap(qe[t]);

    // ---- pack q to f16 pairs ----
    h2 q2[8];
    #pragma unroll
    for (int j = 0; j < 8; ++j) q2[j] = pkrtz(accQ[2 * j], accQ[2 * j + 1]);

    __syncthreads();   // K/V staged

    const int rowsel = (g < 4) ? 1 : 0;

    // ---- Phase A: 49 logits, 2 positions in flight ----
    float lg[K2];
    const unsigned* kb = s_ku + h * 8;
    #pragma unroll
    for (int tp = 0; tp < 24; ++tp) {
        const int t0 = 2 * tp, t1 = t0 + 1;
        const int ki0 = t0 / KK, kj0 = t0 - ki0 * KK;
        const int ki1 = t1 / KK, kj1 = t1 - ki1 * KK;
        const uint2* kp0 = (const uint2*)(kb + ((ty + ki0) * HS + tx + kj0) * KDW);
        const uint2* kp1 = (const uint2*)(kb + ((ty + ki1) * HS + tx + kj1) * KDW);
        uint2 a0 = kp0[0], a1 = kp0[1], a2 = kp0[2], a3 = kp0[3];
        uint2 b0 = kp1[0], b1 = kp1[1], b2 = kp1[2], b3 = kp1[3];
        float p0 = 0.f, p1 = 0.f;
        p0 = dot2u(a0.x, q2[0], p0);  p1 = dot2u(b0.x, q2[0], p1);
        p0 = dot2u(a0.y, q2[1], p0);  p1 = dot2u(b0.y, q2[1], p1);
        p0 = dot2u(a1.x, q2[2], p0);  p1 = dot2u(b1.x, q2[2], p1);
        p0 = dot2u(a1.y, q2[3], p0);  p1 = dot2u(b1.y, q2[3], p1);
        p0 = dot2u(a2.x, q2[4], p0);  p1 = dot2u(b2.x, q2[4], p1);
        p0 = dot2u(a2.y, q2[5], p0);  p1 = dot2u(b2.y, q2[5], p1);
        p0 = dot2u(a3.x, q2[6], p0);  p1 = dot2u(b3.x, q2[6], p1);
        p0 = dot2u(a3.y, q2[7], p0);  p1 = dot2u(b3.y, q2[7], p1);
        lg[t0] = p0 + pswap(p0) + (rowsel ? qe[ki0] : qe[kj0]);
        lg[t1] = p1 + pswap(p1) + (rowsel ? qe[ki1] : qe[kj1]);
    }
    {   // t = 48 (ki=6, kj=6)
        const uint2* kp = (const uint2*)(kb + ((ty + 6) * HS + tx + 6) * KDW);
        uint2 a0 = kp[0], a1 = kp[1], a2 = kp[2], a3 = kp[3];
        float p0 = 0.f;
        p0 = dot2u(a0.x, q2[0], p0); p0 = dot2u(a0.y, q2[1], p0);
        p0 = dot2u(a1.x, q2[2], p0); p0 = dot2u(a1.y, q2[3], p0);
        p0 = dot2u(a2.x, q2[4], p0); p0 = dot2u(a2.y, q2[5], p0);
        p0 = dot2u(a3.x, q2[6], p0); p0 = dot2u(a3.y, q2[7], p0);
        lg[48] = p0 + pswap(p0) + qe[6];
    }

    // ---- Phase B: tree max, independent exps, tree sum ----
    float m0 = lg[0], m1 = lg[1], m2 = lg[2], m3 = lg[3];
    #pragma unroll
    for (int t = 4; t < 48; t += 4) {
        m0 = fmaxf(m0, lg[t]);
        m1 = fmaxf(m1, lg[t + 1]);
        m2 = fmaxf(m2, lg[t + 2]);
        m3 = fmaxf(m3, lg[t + 3]);
    }
    const float mx = fmaxf(fmaxf(m0, m1), fmaxf(m2, fmaxf(m3, lg[48])));

    float s0 = 0.f, s1 = 0.f, s2 = 0.f, s3 = 0.f;
    #pragma unroll
    for (int t = 0; t < K2; ++t) {
        float pe = __expf(lg[t] - mx);
        lg[t] = pe;
        if ((t & 3) == 0) s0 += pe;
        else if ((t & 3) == 1) s1 += pe;
        else if ((t & 3) == 2) s2 += pe;
        else s3 += pe;
    }
    const float s = (s0 + s1) + (s2 + s3);

    // ---- PV: 2 positions in flight, pure f16 fma accumulation ----
    __half2 o2[8];
    #pragma unroll
    for (int j = 0; j < 8; ++j) o2[j] = __float2half2_rn(0.f);

    const unsigned* vb = s_vu + h * 8;
    #pragma unroll
    for (int tp = 0; tp < 24; ++tp) {
        const int t0 = 2 * tp, t1 = t0 + 1;
        const int ki0 = t0 / KK, kj0 = t0 - ki0 * KK;
        const int ki1 = t1 / KK, kj1 = t1 - ki1 * KK;
        const uint2* vp0 = (const uint2*)(vb + ((ty + ki0) * HS + tx + kj0) * KDW);
        const uint2* vp1 = (const uint2*)(vb + ((ty + ki1) * HS + tx + kj1) * KDW);
        uint2 a0 = vp0[0], a1 = vp0[1], a2 = vp0[2], a3 = vp0[3];
        uint2 b0 = vp1[0], b1 = vp1[1], b2 = vp1[2], b3 = vp1[3];
        const __half2 pe0 = __float2half2_rn(lg[t0]);
        const __half2 pe1 = __float2half2_rn(lg[t1]);
        U32H c0, c1, c2, c3, c4, c5, c6, c7;
        c0.u = a0.x; c1.u = a0.y; c2.u = a1.x; c3.u = a1.y;
        c4.u = a2.x; c5.u = a2.y; c6.u = a3.x; c7.u = a3.y;
        o2[0] = __hfma2(c0.p, pe0, o2[0]);
        o2[1] = __hfma2(c1.p, pe0, o2[1]);
        o2[2] = __hfma2(c2.p, pe0, o2[2]);
        o2[3] = __hfma2(c3.p, pe0, o2[3]);
        o2[4] = __hfma2(c4.p, pe0, o2[4]);
        o2[5] = __hfma2(c5.p, pe0, o2[5]);
        o2[6] = __hfma2(c6.p, pe0, o2[6]);
        o2[7] = __hfma2(c7.p, pe0, o2[7]);
        c0.u = b0.x; c1.u = b0.y; c2.u = b1.x; c3.u = b1.y;
        c4.u = b2.x; c5.u = b2.y; c6.u = b3.x; c7.u = b3.y;
        o2[0] = __hfma2(c0.p, pe1, o2[0]);
        o2[1] = __hfma2(c1.p, pe1, o2[1]);
        o2[2] = __hfma2(c2.p, pe1, o2[2]);
        o2[3] = __hfma2(c3.p, pe1, o2[3]);
        o2[4] = __hfma2(c4.p, pe1, o2[4]);
        o2[5] = __hfma2(c5.p, pe1, o2[5]);
        o2[6] = __hfma2(c6.p, pe1, o2[6]);
        o2[7] = __hfma2(c7.p, pe1, o2[7]);
    }
    {   // t = 48
        const uint2* vp = (const uint2*)(vb + ((ty + 6) * HS + tx + 6) * KDW);
        uint2 a0 = vp[0], a1 = vp[1], a2 = vp[2], a3 = vp[3];
        const __half2 pe0 = __float2half2_rn(lg[48]);
        U32H c0, c1, c2, c3, c4, c5, c6, c7;
        c0.u = a0.x; c1.u = a0.y; c2.u = a1.x; c3.u = a1.y;
        c4.u = a2.x; c5.u = a2.y; c6.u = a3.x; c7.u = a3.y;
        o2[0] = __hfma2(c0.p, pe0, o2[0]);
        o2[1] = __hfma2(c1.p, pe0, o2[1]);
        o2[2] = __hfma2(c2.p, pe0, o2[2]);
        o2[3] = __hfma2(c3.p, pe0, o2[3]);
        o2[4] = __hfma2(c4.p, pe0, o2[4]);
        o2[5] = __hfma2(c5.p, pe0, o2[5]);
        o2[6] = __hfma2(c6.p, pe0, o2[6]);
        o2[7] = __hfma2(c7.p, pe0, o2[7]);
    }

    // ---- write 16 channels ----
    const float inv = 1.0f / s;
    float* op = out + (size_t)(b * 256 + g * 32 + h * 16) * 4096 + yy * 64 + xx;
    #pragma unroll
    for (int j = 0; j < 8; ++j) {
        float2 f = __half22float2(o2[j]);
        op[(2 * j) * 4096]     = f.x * inv;
        op[(2 * j + 1) * 4096] = f.y * inv;
    }
}

extern "C" void kernel_launch(void* const* d_in, const int* in_sizes, int n_in,
                              void* d_out, int out_size, void* d_ws, size_t ws_size,
                              hipStream_t stream) {
    const float* x       = (const float*)d_in[0];
    const float* wq      = (const float*)d_in[1];
    const float* wk      = (const float*)d_in[2];
    const float* wv      = (const float*)d_in[3];
    const float* row_emb = (const float*)d_in[4];
    const float* col_emb = (const float*)d_in[5];
    float* out = (float*)d_out;

    dim3 grid(4, 8, 32);   // (W/16, H/8, B*G), remapped inside (XCD swizzle)
    dim3 block(256);
    sasa_fused_kernel<<<grid, block, 0, stream>>>(x, wq, wk, wv, row_emb, col_emb, out);
}

// Round 33
// 40.053 us; speedup vs baseline: 1.4567x; 1.0279x over previous
//
#include <hip/hip_runtime.h>
#include <hip/hip_bf16.h>
#include <hip/hip_fp16.h>

// SASA local self-attention, fused. FINAL (round 27 kernel, measured 40.1us):
//  - MFMA K/V halo projection (mfma_f32_16x16x32_f16, 124 MFMAs/block)
//  - packed-f16 dot2 QK^T + hfma2 PV, two-pass register softmax
//  - XCD-bijective block swizzle (halo re-reads are L2 hits, FETCH 8.4MB)
//  - KDW=18 bank-spread LDS layout; DPP lane^1 reduces (no LDS shfl)
// Session: 293us (r1) -> 108 (spill fix) -> 83 (bank conflicts) -> 62 (f16)
//          -> 49.9 (latency/swizzle) -> 40.1 (MFMA projection). 7.3x total.
// B=4, CIN=COUT=256, H=W=64, G=8, CG=32, K=7, PAD=3.
#define TS   16
#define HS   22
#define HP   484
#define KDW  18          // u32 stride per halo pixel (72B)
#define KK   7
#define K2   49

typedef _Float16 h2   __attribute__((ext_vector_type(2)));
typedef _Float16 f16x8 __attribute__((ext_vector_type(8)));
typedef float    f32x4 __attribute__((ext_vector_type(4)));
union U32H { unsigned u; h2 h; __half2 p; };

__device__ __forceinline__ h2 pkrtz(float a, float b) {
    auto r = __builtin_amdgcn_cvt_pkrtz(a, b);
    union { decltype(r) i; h2 o; } c; c.i = r;
    return c.o;
}
__device__ __forceinline__ float dot2(h2 a, h2 b, float c) {
#if __has_builtin(__builtin_amdgcn_fdot2)
    return __builtin_amdgcn_fdot2(a, b, c, false);
#else
    return fmaf((float)a.x, (float)b.x, fmaf((float)a.y, (float)b.y, c));
#endif
}
__device__ __forceinline__ float dot2u(unsigned wu, h2 b, float c) {
    U32H w; w.u = wu; return dot2(w.h, b, c);
}
__device__ __forceinline__ float pswap(float v) {
#if __has_builtin(__builtin_amdgcn_mov_dpp)
    int j = __builtin_amdgcn_mov_dpp(__float_as_int(v), 0xB1, 0xF, 0xF, true);
    return __int_as_float(j);
#else
    return __shfl_xor(v, 1, 64);
#endif
}

__global__ __attribute__((amdgpu_flat_work_group_size(512, 512), amdgpu_waves_per_eu(4, 4)))
void sasa_fused_kernel(const float* __restrict__ x,
                       const float* __restrict__ wq,
                       const float* __restrict__ wk,
                       const float* __restrict__ wv,
                       const float* __restrict__ row_emb,
                       const float* __restrict__ col_emb,
                       float* __restrict__ out)
{
    __shared__ h2       s_w[1536];         // [m(k,v,q)*2+hh][cp][co], 6 KB
    __shared__ float    s_emb[224];        // E[c][t], 0.9 KB
    __shared__ unsigned s_ku[HP * KDW];    // K halo, f16 pairs, 34.8 KB
    __shared__ unsigned s_vu[HP * KDW];    // V halo, f16 pairs, 34.8 KB

    const int tid = threadIdx.x;

    // ---- XCD-bijective swizzle (r15) ----
    const int lin  = blockIdx.x + (blockIdx.y << 2) + (blockIdx.z << 4);
    const int xcd  = lin & 7;
    const int slot = lin >> 3;
    const int zg   = xcd + ((slot >> 4) << 3);
    const int sp   = slot & 15;
    const int b    = zg >> 3;
    const int g    = zg & 7;
    const int y0   = (sp >> 2) * TS;
    const int x0   = (sp & 3) * TS;

    const float* xg = x + (size_t)(b * 256 + g * 32) * 4096;

    // ---- stage all 3 weight matrices as f16 pairs + emb slice ----
    {
        const int cp  = tid & 15;
        const int cog = tid >> 4;
        const int hh  = cog >> 4;
        const int co  = cog & 15;
        const int di  = (hh * 16 + cp) * 16 + co;
        const float2* wk2 = (const float2*)(wk + g * 1024);
        const float2* wv2 = (const float2*)(wv + g * 1024);
        const float2* wq2 = (const float2*)(wq + g * 1024);
        float2 a = wk2[tid]; s_w[di]        = pkrtz(a.x, a.y);
        float2 v = wv2[tid]; s_w[512 + di]  = pkrtz(v.x, v.y);
        float2 q = wq2[tid]; s_w[1024 + di] = pkrtz(q.x, q.y);
    }
    if (tid < 224) {
        int c = tid / KK, t = tid - c * KK;
        s_emb[tid] = (g < 4) ? row_emb[(g * 32 + c) * KK + t]
                             : col_emb[((g - 4) * 32 + c) * KK + t];
    }
    __syncthreads();

    // ---- K/V halo projection via MFMA (wave-tiled) ----
    {
        const int lane = tid & 63;
        const int wid  = tid >> 6;        // 0..7
        const int lrow = lane & 15;       // A row / B col / D col
        const int lgrp = lane >> 4;       // k group 0..3

        f16x8 bk0, bk1, bv0, bv1;
        #pragma unroll
        for (int j = 0; j < 4; ++j) {
            const int cp = lgrp * 4 + j;
            h2 pk0 = s_w[(0 * 16 + cp) * 16 + lrow];
            h2 pk1 = s_w[(1 * 16 + cp) * 16 + lrow];
            h2 pv0 = s_w[512 + (0 * 16 + cp) * 16 + lrow];
            h2 pv1 = s_w[512 + (1 * 16 + cp) * 16 + lrow];
            bk0[2 * j] = pk0.x; bk0[2 * j + 1] = pk0.y;
            bk1[2 * j] = pk1.x; bk1[2 * j + 1] = pk1.y;
            bv0[2 * j] = pv0.x; bv0[2 * j + 1] = pv0.y;
            bv1[2 * j] = pv1.x; bv1[2 * j + 1] = pv1.y;
        }

        _Float16* sk16 = (_Float16*)s_ku;
        _Float16* sv16 = (_Float16*)s_vu;
        const f32x4 zero = {0.f, 0.f, 0.f, 0.f};

        #pragma unroll 1
        for (int t = wid; t < 31; t += 8) {
            const int hp = t * 16 + lrow;
            f16x8 a;
            bool valid = false;
            int gy = 0, gx = 0;
            if (hp < HP) {
                const int hy = hp / HS, hx = hp - hy * HS;
                gy = y0 + hy - 3; gx = x0 + hx - 3;
                valid = ((unsigned)gy < 64u) && ((unsigned)gx < 64u);
            }
            if (valid) {
                const float* xp = xg + gy * 64 + gx + (size_t)(lgrp * 8) * 4096;
                #pragma unroll
                for (int i2 = 0; i2 < 4; ++i2) {
                    h2 pr = pkrtz(xp[(2 * i2) * 4096], xp[(2 * i2 + 1) * 4096]);
                    a[2 * i2] = pr.x; a[2 * i2 + 1] = pr.y;
                }
            } else {
                #pragma unroll
                for (int i = 0; i < 8; ++i) a[i] = (_Float16)0.f;
            }

            f32x4 dk0 = __builtin_amdgcn_mfma_f32_16x16x32_f16(a, bk0, zero, 0, 0, 0);
            f32x4 dk1 = __builtin_amdgcn_mfma_f32_16x16x32_f16(a, bk1, zero, 0, 0, 0);
            f32x4 dv0 = __builtin_amdgcn_mfma_f32_16x16x32_f16(a, bv0, zero, 0, 0, 0);
            f32x4 dv1 = __builtin_amdgcn_mfma_f32_16x16x32_f16(a, bv1, zero, 0, 0, 0);

            #pragma unroll
            for (int r = 0; r < 4; ++r) {
                const int hpo = t * 16 + lgrp * 4 + r;
                if (hpo < HP) {
                    const int base = hpo * 36;
                    sk16[base + lrow]      = (_Float16)dk0[r];
                    sk16[base + 16 + lrow] = (_Float16)dk1[r];
                    sv16[base + lrow]      = (_Float16)dv0[r];
                    sv16[base + 16 + lrow] = (_Float16)dv1[r];
                }
            }
        }
    }

    // ---- q projection: thread (p, h) owns 16 q channels ----
    const int p  = tid >> 1;
    const int h  = tid & 1;
    const int tx = p & 15, ty = p >> 4;
    const int yy = y0 + ty, xx = x0 + tx;
    float accQ[16];
    #pragma unroll
    for (int c = 0; c < 16; ++c) accQ[c] = 0.f;
    {
        const float* xp = xg + yy * 64 + xx;
        h2 xv2[16];
        #pragma unroll
        for (int cp = 0; cp < 16; ++cp)
            xv2[cp] = pkrtz(xp[(2 * cp) * 4096], xp[(2 * cp + 1) * 4096]);
        const h2* wqp = s_w + 1024 + h * 256;
        #pragma unroll
        for (int cp = 0; cp < 16; ++cp) {
            h2 xv = xv2[cp];
            const uint4* wqr = (const uint4*)(wqp + cp * 16);
            uint4 qw[4] = { wqr[0], wqr[1], wqr[2], wqr[3] };
            const unsigned* qwu = (const unsigned*)qw;
            #pragma unroll
            for (int co = 0; co < 16; ++co)
                accQ[co] = dot2u(qwu[co], xv, accQ[co]);
        }
    }

    // ---- qe[7] = q . emb, pair-combined via DPP ----
    float qe[KK];
    #pragma unroll
    for (int t = 0; t < KK; ++t) {
        float a = 0.f;
        #pragma unroll
        for (int c = 0; c < 16; ++c)
            a = fmaf(accQ[c], s_emb[(h * 16 + c) * KK + t], a);
        qe[t] = a + 0.f;
    }
    #pragma unroll
    for (int t = 0; t < KK; ++t)
        qe[t] += pswap(qe[t]);

    // ---- pack q to f16 pairs ----
    h2 q2[8];
    #pragma unroll
    for (int j = 0; j < 8; ++j) q2[j] = pkrtz(accQ[2 * j], accQ[2 * j + 1]);

    __syncthreads();   // s_ku / s_vu complete

    const int rowsel = (g < 4) ? 1 : 0;

    // ---- Phase A: 49 logits, 2 positions in flight, DPP pair-combine ----
    float lg[K2];
    const unsigned* kb = s_ku + h * 8;
    #pragma unroll
    for (int tp = 0; tp < 24; ++tp) {
        const int t0 = 2 * tp, t1 = t0 + 1;
        const int ki0 = t0 / KK, kj0 = t0 - ki0 * KK;
        const int ki1 = t1 / KK, kj1 = t1 - ki1 * KK;
        const uint2* kp0 = (const uint2*)(kb + ((ty + ki0) * HS + tx + kj0) * KDW);
        const uint2* kp1 = (const uint2*)(kb + ((ty + ki1) * HS + tx + kj1) * KDW);
        uint2 a0 = kp0[0], a1 = kp0[1], a2 = kp0[2], a3 = kp0[3];
        uint2 b0 = kp1[0], b1 = kp1[1], b2 = kp1[2], b3 = kp1[3];
        float p0 = 0.f, p1 = 0.f;
        p0 = dot2u(a0.x, q2[0], p0);  p1 = dot2u(b0.x, q2[0], p1);
        p0 = dot2u(a0.y, q2[1], p0);  p1 = dot2u(b0.y, q2[1], p1);
        p0 = dot2u(a1.x, q2[2], p0);  p1 = dot2u(b1.x, q2[2], p1);
        p0 = dot2u(a1.y, q2[3], p0);  p1 = dot2u(b1.y, q2[3], p1);
        p0 = dot2u(a2.x, q2[4], p0);  p1 = dot2u(b2.x, q2[4], p1);
        p0 = dot2u(a2.y, q2[5], p0);  p1 = dot2u(b2.y, q2[5], p1);
        p0 = dot2u(a3.x, q2[6], p0);  p1 = dot2u(b3.x, q2[6], p1);
        p0 = dot2u(a3.y, q2[7], p0);  p1 = dot2u(b3.y, q2[7], p1);
        lg[t0] = p0 + pswap(p0) + (rowsel ? qe[ki0] : qe[kj0]);
        lg[t1] = p1 + pswap(p1) + (rowsel ? qe[ki1] : qe[kj1]);
    }
    {   // t = 48 (ki=6, kj=6)
        const uint2* kp = (const uint2*)(kb + ((ty + 6) * HS + tx + 6) * KDW);
        uint2 a0 = kp[0], a1 = kp[1], a2 = kp[2], a3 = kp[3];
        float p0 = 0.f;
        p0 = dot2u(a0.x, q2[0], p0); p0 = dot2u(a0.y, q2[1], p0);
        p0 = dot2u(a1.x, q2[2], p0); p0 = dot2u(a1.y, q2[3], p0);
        p0 = dot2u(a2.x, q2[4], p0); p0 = dot2u(a2.y, q2[5], p0);
        p0 = dot2u(a3.x, q2[6], p0); p0 = dot2u(a3.y, q2[7], p0);
        lg[48] = p0 + pswap(p0) + qe[6];
    }

    // ---- Phase B: tree max, independent exps, tree sum ----
    float m0 = lg[0], m1 = lg[1], m2 = lg[2], m3 = lg[3];
    #pragma unroll
    for (int t = 4; t < 48; t += 4) {
        m0 = fmaxf(m0, lg[t]);
        m1 = fmaxf(m1, lg[t + 1]);
        m2 = fmaxf(m2, lg[t + 2]);
        m3 = fmaxf(m3, lg[t + 3]);
    }
    const float mx = fmaxf(fmaxf(m0, m1), fmaxf(m2, fmaxf(m3, lg[48])));

    float s0 = 0.f, s1 = 0.f, s2 = 0.f, s3 = 0.f;
    #pragma unroll
    for (int t = 0; t < K2; ++t) {
        float pe = __expf(lg[t] - mx);
        lg[t] = pe;
        if ((t & 3) == 0) s0 += pe;
        else if ((t & 3) == 1) s1 += pe;
        else if ((t & 3) == 2) s2 += pe;
        else s3 += pe;
    }
    const float s = (s0 + s1) + (s2 + s3);

    // ---- PV: 2 positions in flight, pure f16 fma accumulation ----
    __half2 o2[8];
    #pragma unroll
    for (int j = 0; j < 8; ++j) o2[j] = __float2half2_rn(0.f);

    const unsigned* vb = s_vu + h * 8;
    #pragma unroll
    for (int tp = 0; tp < 24; ++tp) {
        const int t0 = 2 * tp, t1 = t0 + 1;
        const int ki0 = t0 / KK, kj0 = t0 - ki0 * KK;
        const int ki1 = t1 / KK, kj1 = t1 - ki1 * KK;
        const uint2* vp0 = (const uint2*)(vb + ((ty + ki0) * HS + tx + kj0) * KDW);
        const uint2* vp1 = (const uint2*)(vb + ((ty + ki1) * HS + tx + kj1) * KDW);
        uint2 a0 = vp0[0], a1 = vp0[1], a2 = vp0[2], a3 = vp0[3];
        uint2 b0 = vp1[0], b1 = vp1[1], b2 = vp1[2], b3 = vp1[3];
        const __half2 pe0 = __float2half2_rn(lg[t0]);
        const __half2 pe1 = __float2half2_rn(lg[t1]);
        U32H c0, c1, c2, c3, c4, c5, c6, c7;
        c0.u = a0.x; c1.u = a0.y; c2.u = a1.x; c3.u = a1.y;
        c4.u = a2.x; c5.u = a2.y; c6.u = a3.x; c7.u = a3.y;
        o2[0] = __hfma2(c0.p, pe0, o2[0]);
        o2[1] = __hfma2(c1.p, pe0, o2[1]);
        o2[2] = __hfma2(c2.p, pe0, o2[2]);
        o2[3] = __hfma2(c3.p, pe0, o2[3]);
        o2[4] = __hfma2(c4.p, pe0, o2[4]);
        o2[5] = __hfma2(c5.p, pe0, o2[5]);
        o2[6] = __hfma2(c6.p, pe0, o2[6]);
        o2[7] = __hfma2(c7.p, pe0, o2[7]);
        c0.u = b0.x; c1.u = b0.y; c2.u = b1.x; c3.u = b1.y;
        c4.u = b2.x; c5.u = b2.y; c6.u = b3.x; c7.u = b3.y;
        o2[0] = __hfma2(c0.p, pe1, o2[0]);
        o2[1] = __hfma2(c1.p, pe1, o2[1]);
        o2[2] = __hfma2(c2.p, pe1, o2[2]);
        o2[3] = __hfma2(c3.p, pe1, o2[3]);
        o2[4] = __hfma2(c4.p, pe1, o2[4]);
        o2[5] = __hfma2(c5.p, pe1, o2[5]);
        o2[6] = __hfma2(c6.p, pe1, o2[6]);
        o2[7] = __hfma2(c7.p, pe1, o2[7]);
    }
    {   // t = 48
        const uint2* vp = (const uint2*)(vb + ((ty + 6) * HS + tx + 6) * KDW);
        uint2 a0 = vp[0], a1 = vp[1], a2 = vp[2], a3 = vp[3];
        const __half2 pe0 = __float2half2_rn(lg[48]);
        U32H c0, c1, c2, c3, c4, c5, c6, c7;
        c0.u = a0.x; c1.u = a0.y; c2.u = a1.x; c3.u = a1.y;
        c4.u = a2.x; c5.u = a2.y; c6.u = a3.x; c7.u = a3.y;
        o2[0] = __hfma2(c0.p, pe0, o2[0]);
        o2[1] = __hfma2(c1.p, pe0, o2[1]);
        o2[2] = __hfma2(c2.p, pe0, o2[2]);
        o2[3] = __hfma2(c3.p, pe0, o2[3]);
        o2[4] = __hfma2(c4.p, pe0, o2[4]);
        o2[5] = __hfma2(c5.p, pe0, o2[5]);
        o2[6] = __hfma2(c6.p, pe0, o2[6]);
        o2[7] = __hfma2(c7.p, pe0, o2[7]);
    }

    // ---- write 16 channels ----
    const float inv = 1.0f / s;
    float* op = out + (size_t)(b * 256 + g * 32 + h * 16) * 4096 + yy * 64 + xx;
    #pragma unroll
    for (int j = 0; j < 8; ++j) {
        float2 f = __half22float2(o2[j]);
        op[(2 * j) * 4096]     = f.x * inv;
        op[(2 * j + 1) * 4096] = f.y * inv;
    }
}

extern "C" void kernel_launch(void* const* d_in, const int* in_sizes, int n_in,
                              void* d_out, int out_size, void* d_ws, size_t ws_size,
                              hipStream_t stream) {
    const float* x       = (const float*)d_in[0];
    const float* wq      = (const float*)d_in[1];
    const float* wk      = (const float*)d_in[2];
    const float* wv      = (const float*)d_in[3];
    const float* row_emb = (const float*)d_in[4];
    const float* col_emb = (const float*)d_in[5];
    float* out = (float*)d_out;

    dim3 grid(4, 4, 32);   // remapped inside kernel (XCD-bijective swizzle)
    dim3 block(512);
    sasa_fused_kernel<<<grid, block, 0, stream>>>(x, wq, wk, wv, row_emb, col_emb, out);
}